// Round 6
// baseline (160.065 us; speedup 1.0000x reference)
//
#include <hip/hip_runtime.h>

typedef float floatx4 __attribute__((ext_vector_type(4)));
typedef int intx4 __attribute__((ext_vector_type(4)));
typedef int intx8 __attribute__((ext_vector_type(8)));
typedef __attribute__((address_space(1))) const void gvoid;
typedef __attribute__((address_space(3))) void svoid;

#define SCALE_POS 2.0f
#define SCALE_NEG 40.0f
#define THRESH 0.5f
#define MARGIN 0.1f
#define EPSV 1e-5f

// ---- kernel 1: fp32 -> fp8 e4m3 (OCP, RNE via HW cvt) + scalar init ----
__global__ void k_init(const float* __restrict__ feats,
                       unsigned char* __restrict__ f8,
                       float* __restrict__ out,
                       unsigned* __restrict__ cnt,
                       int total4) {
    int i = blockIdx.x * blockDim.x + threadIdx.x;
    if (i < total4) {
        float4 v = ((const float4*)feats)[i];
        int w = 0;
        w = __builtin_amdgcn_cvt_pk_fp8_f32(v.x, v.y, w, false);  // bytes 0,1
        w = __builtin_amdgcn_cvt_pk_fp8_f32(v.z, v.w, w, true);   // bytes 2,3
        ((int*)f8)[i] = w;
    }
    if (i == 0) { out[0] = 0.f; cnt[0] = 0u; }
}

// =====================================================================
// kernel 2 (R22): FUSED persistent pass.
//   phase 1: MX-fp8 GEMM, 128x128 tile, 4 waves 2x2 (R19/R20 verified
//            K-loop, gload_lds staging — all 5 staging variants measured
//            equal, this one is VGPR-cheapest at 64).
//   phase 2: min-pos/max-neg partials -> unique-writer slots (R20).
//   ---- grid rendezvous: RELEASE fetch_add + ACQUIRE spin (G16:
//        device-scope atomics handle cross-XCD L2 non-coherence).
//        528 blocks <= 3 blocks/CU x 256 CU = 768 co-resident slots
//        (enforced by __launch_bounds__(256,3); LDS 35.8KB -> 4/CU),
//        so all blocks are resident and the spin cannot deadlock.
//   phase 3: per-block gate reduce (64 slots, coalesced).
//   phase 4: gated exp sums STRAIGHT FROM the fp32 acc registers ->
//            unique-writer psP/psN slots (same partition, verified).
// Deleted vs R21: simh (17MB write + 17MB read), k_sum2f dispatch,
// k_stats dispatch — the ~45us pass-2 kernel and 2 launch overheads.
// =====================================================================
__global__ void __launch_bounds__(256, 3)
k_fused(const unsigned char* __restrict__ f8,
        const int* __restrict__ labels,
        float* __restrict__ pmin,     // [64][B] partial min-pos
        float* __restrict__ pmax,     // [64][B] partial max-neg
        float* __restrict__ psP,      // [64][B] partial pos-exp sums
        float* __restrict__ psN,      // [64][B] partial neg-exp sums
        unsigned* __restrict__ cnt,   // done-counter (zeroed by k_init)
        int D, int nb, int NTtot) {
    __shared__ __align__(16) unsigned char As[128 * 128];  // 16 KB
    __shared__ __align__(16) unsigned char Bs[128 * 128];  // 16 KB
    __shared__ int labR[128], labC[128];
    __shared__ float gNR[128], gPR[128], gNC[128], gPC[128];

    const int Bsz = nb * 128;

    // bijective XCD-aware swizzle: 528 tiles = 8 XCDs x 66
    const int bid0 = blockIdx.x;
    const int t = (bid0 & 7) * 66 + (bid0 >> 3);
    int rb = 0, rem = t;
    while (rem >= nb - rb) { rem -= nb - rb; ++rb; }
    const int cb = rb + rem;
    const int rowBase = rb * 128;
    const int colBase = cb * 128;

    const int tid = threadIdx.x;        // 0..255
    const int lane = tid & 63;
    const int wave = tid >> 6;          // 0..3
    const int wr = wave >> 1;           // row half of output tile
    const int wc = wave & 1;            // col half of output tile
    const int q = lane >> 4;
    const int cIn = lane & 15;

    if (tid < 128) labR[tid] = labels[rowBase + tid];
    else           labC[tid - 128] = labels[colBase + (tid - 128)];

    // staging: 32 chunks of 1KB (8 rows x 128B). Wave handles 8.
    const int subrow = lane >> 3;
    const int swz = (lane & 7) ^ subrow;     // logical 16B-block index
    const unsigned char* gP[8];
    unsigned char* lP[8];
#pragma unroll
    for (int j = 0; j < 8; ++j) {
        const int c = wave * 8 + j;          // 0..31
        const int grow = (c < 16) ? (rowBase + c * 8 + subrow)
                                  : (colBase + (c - 16) * 8 + subrow);
        gP[j] = f8 + (size_t)grow * D + swz * 16;
        lP[j] = ((c < 16) ? (As + c * 1024) : (Bs + (c - 16) * 1024)) + lane * 16;
    }

    // fragment LDS offsets: row r, 32B k-group q = logical blocks 2q,2q+1
    // physical p = blk ^ (r&7)
    int aOff0[4], aOff1[4], bOff0[4], bOff1[4];
#pragma unroll
    for (int i = 0; i < 4; ++i) {
        const int rA = wr * 64 + i * 16 + cIn;
        aOff0[i] = rA * 128 + ((2 * q) ^ (rA & 7)) * 16;
        aOff1[i] = rA * 128 + ((2 * q + 1) ^ (rA & 7)) * 16;
        const int rB = wc * 64 + i * 16 + cIn;
        bOff0[i] = rB * 128 + ((2 * q) ^ (rB & 7)) * 16;
        bOff1[i] = rB * 128 + ((2 * q + 1) ^ (rB & 7)) * 16;
    }

    floatx4 acc[4][4] = {};

    const int KT = D >> 7;               // 8 iters of K=128
    for (int kt = 0; kt < KT; ++kt) {
        const int kOff = kt * 128;
        __syncthreads();                 // prev readers done (+labels at kt=0)
#pragma unroll
        for (int j = 0; j < 8; ++j)
            __builtin_amdgcn_global_load_lds((gvoid*)(gP[j] + kOff), (svoid*)lP[j], 16, 0, 0);
        __syncthreads();                 // stage landed (implicit vmcnt drain)

        intx8 a[4], b[4];
#pragma unroll
        for (int i = 0; i < 4; ++i) {
            intx4 lo = *(const intx4*)(As + aOff0[i]);
            intx4 hi = *(const intx4*)(As + aOff1[i]);
            a[i] = __builtin_shufflevector(lo, hi, 0, 1, 2, 3, 4, 5, 6, 7);
        }
#pragma unroll
        for (int i = 0; i < 4; ++i) {
            intx4 lo = *(const intx4*)(Bs + bOff0[i]);
            intx4 hi = *(const intx4*)(Bs + bOff1[i]);
            b[i] = __builtin_shufflevector(lo, hi, 0, 1, 2, 3, 4, 5, 6, 7);
        }
#pragma unroll
        for (int i = 0; i < 4; ++i)
#pragma unroll
            for (int j2 = 0; j2 < 4; ++j2)
                acc[i][j2] = __builtin_amdgcn_mfma_scale_f32_16x16x128_f8f6f4(
                    a[i], b[j2], acc[i][j2], 0, 0,       // cbsz=fp8, blgp=fp8
                    0, 0x7f7f7f7f,                       // opsel_a, scale_a (unity E8M0)
                    0, 0x7f7f7f7f);                      // opsel_b, scale_b
    }

    int rLabv[16];
#pragma unroll
    for (int mi = 0; mi < 4; ++mi)
#pragma unroll
        for (int rr = 0; rr < 4; ++rr)
            rLabv[mi * 4 + rr] = labR[wr * 64 + mi * 16 + q * 4 + rr];
    int cLabv[4];
#pragma unroll
    for (int ni = 0; ni < 4; ++ni)
        cLabv[ni] = labC[wc * 64 + ni * 16 + cIn];

    const bool offd = (rb != cb);

    // ---- phase 2: stat partials, unique-writer slots (R20) ----
    {
        float* pmnRow = pmin + (size_t)(2 * cb + wc) * Bsz + rowBase;
        float* pmxRow = pmax + (size_t)(2 * cb + wc) * Bsz + rowBase;
#pragma unroll
        for (int mi = 0; mi < 4; ++mi)
#pragma unroll
            for (int rr = 0; rr < 4; ++rr) {
                const int rLoc = wr * 64 + mi * 16 + q * 4 + rr;
                const int rLab = rLabv[mi * 4 + rr];
                float vmin = 1e30f, vmax = -1e30f;
#pragma unroll
                for (int ni = 0; ni < 4; ++ni) {
                    float s = acc[mi][ni][rr];
                    if (rLab == cLabv[ni]) {
                        if (s < 1.0f - EPSV) vmin = fminf(vmin, s);
                    } else {
                        vmax = fmaxf(vmax, s);
                    }
                }
#pragma unroll
                for (int off = 8; off; off >>= 1) {
                    vmin = fminf(vmin, __shfl_xor(vmin, off, 16));
                    vmax = fmaxf(vmax, __shfl_xor(vmax, off, 16));
                }
                if (cIn == 0) {
                    pmnRow[rLoc] = vmin;
                    pmxRow[rLoc] = vmax;
                }
            }
    }
    if (offd) {
        float* pmnCol = pmin + (size_t)(2 * rb + wr) * Bsz + colBase;
        float* pmxCol = pmax + (size_t)(2 * rb + wr) * Bsz + colBase;
#pragma unroll
        for (int ni = 0; ni < 4; ++ni) {
            const int cLab = cLabv[ni];
            float vmin = 1e30f, vmax = -1e30f;
#pragma unroll
            for (int mi = 0; mi < 4; ++mi)
#pragma unroll
                for (int rr = 0; rr < 4; ++rr) {
                    float s = acc[mi][ni][rr];
                    if (rLabv[mi * 4 + rr] == cLab) {
                        if (s < 1.0f - EPSV) vmin = fminf(vmin, s);
                    } else {
                        vmax = fmaxf(vmax, s);
                    }
                }
            vmin = fminf(vmin, __shfl_xor(vmin, 16, 64));
            vmin = fminf(vmin, __shfl_xor(vmin, 32, 64));
            vmax = fmaxf(vmax, __shfl_xor(vmax, 16, 64));
            vmax = fmaxf(vmax, __shfl_xor(vmax, 32, 64));
            if (q == 0) {
                const int cLoc = wc * 64 + ni * 16 + cIn;
                pmnCol[cLoc] = vmin;
                pmxCol[cLoc] = vmax;
            }
        }
    }

    // ---- grid rendezvous: all partials published, then visible ----
    __syncthreads();                       // all waves' stores issued
    if (tid == 0) {
        __hip_atomic_fetch_add(cnt, 1u, __ATOMIC_RELEASE, __HIP_MEMORY_SCOPE_AGENT);
        while (__hip_atomic_load(cnt, __ATOMIC_ACQUIRE, __HIP_MEMORY_SCOPE_AGENT)
               < (unsigned)NTtot)
            __builtin_amdgcn_s_sleep(2);
    }
    __syncthreads();                       // whole block released; acquire done

    // ---- phase 3: gate reduce (rows by tid<128, cols by tid>=128) ----
    {
        const int j = tid & 127;
        const int base = (tid < 128) ? (rowBase + j) : (colBase + j);
        float mn = 1e30f, mx = -1e30f;
        for (int k = 0; k < 64; ++k) {
            mn = fminf(mn, pmin[(size_t)k * Bsz + base]);
            mx = fmaxf(mx, pmax[(size_t)k * Bsz + base]);
        }
        if (tid < 128) { gNR[j] = mn - MARGIN; gPR[j] = mx + MARGIN; }
        else           { gNC[j] = mn - MARGIN; gPC[j] = mx + MARGIN; }
    }
    __syncthreads();

    // ---- phase 4: gated exp sums from live fp32 acc ----
    {
        float gNCv[4], gPCv[4];
#pragma unroll
        for (int ni = 0; ni < 4; ++ni) {
            const int j = wc * 64 + ni * 16 + cIn;
            gNCv[ni] = gNC[j];
            gPCv[ni] = gPC[j];
        }
        float cps[4] = {}, cns[4] = {};
        float* psPRow = psP + (size_t)(2 * cb + wc) * Bsz + rowBase;
        float* psNRow = psN + (size_t)(2 * cb + wc) * Bsz + rowBase;
#pragma unroll
        for (int mi = 0; mi < 4; ++mi)
#pragma unroll
            for (int rr = 0; rr < 4; ++rr) {
                const int rLoc = wr * 64 + mi * 16 + q * 4 + rr;
                const int rLab = rLabv[mi * 4 + rr];
                const float gn = gNR[rLoc];
                const float gp = gPR[rLoc];
                float rp = 0.f, rn = 0.f;
#pragma unroll
                for (int ni = 0; ni < 4; ++ni) {
                    const float s = acc[mi][ni][rr];
                    if (rLab == cLabv[ni]) {
                        if (s < 1.0f - EPSV) {
                            float ev = __expf(-SCALE_POS * (s - THRESH));
                            if (s < gp) rp += ev;
                            if (offd && s < gPCv[ni]) cps[ni] += ev;
                        }
                    } else {
                        float ev = __expf(SCALE_NEG * (s - THRESH));
                        if (s > gn) rn += ev;
                        if (offd && s > gNCv[ni]) cns[ni] += ev;
                    }
                }
#pragma unroll
                for (int off = 8; off; off >>= 1) {
                    rp += __shfl_xor(rp, off, 16);
                    rn += __shfl_xor(rn, off, 16);
                }
                if (cIn == 0) {
                    psPRow[rLoc] = rp;      // unique slot, plain store
                    psNRow[rLoc] = rn;
                }
            }
        if (offd) {
            float* psPCol = psP + (size_t)(2 * rb + wr) * Bsz + colBase;
            float* psNCol = psN + (size_t)(2 * rb + wr) * Bsz + colBase;
#pragma unroll
            for (int ni = 0; ni < 4; ++ni) {
                cps[ni] += __shfl_xor(cps[ni], 16, 64);
                cps[ni] += __shfl_xor(cps[ni], 32, 64);
                cns[ni] += __shfl_xor(cns[ni], 16, 64);
                cns[ni] += __shfl_xor(cns[ni], 32, 64);
                if (q == 0) {
                    const int cLoc = wc * 64 + ni * 16 + cIn;
                    psPCol[cLoc] = cps[ni];
                    psNCol[cLoc] = cns[ni];
                }
            }
        }
    }
}

// =====================================================================
// kernel 3: final reduce -> out[0] (16 blocks, one atomicAdd each)
// =====================================================================
__global__ void __launch_bounds__(256)
k_final(const float* __restrict__ psP, const float* __restrict__ psN,
        float* __restrict__ out, int B) {
    __shared__ float red[4];
    const int r = blockIdx.x * 256 + threadIdx.x;
    float P = 0.f, N = 0.f;
    for (int k = 0; k < 64; ++k) {
        P += psP[(size_t)k * B + r];
        N += psN[(size_t)k * B + r];
    }
    float a = (P > 0.f && N > 0.f)
                  ? log1pf(P) * (1.0f / SCALE_POS) + log1pf(N) * (1.0f / SCALE_NEG)
                  : 0.f;
#pragma unroll
    for (int off = 32; off; off >>= 1) a += __shfl_down(a, off, 64);
    const int tid = threadIdx.x;
    if ((tid & 63) == 0) red[tid >> 6] = a;
    __syncthreads();
    if (tid == 0)
        atomicAdd(out, (red[0] + red[1] + red[2] + red[3]) / (float)B);
}

extern "C" void kernel_launch(void* const* d_in, const int* in_sizes, int n_in,
                              void* d_out, int out_size, void* d_ws, size_t ws_size,
                              hipStream_t stream) {
    const float* feats = (const float*)d_in[0];
    const int* labels = (const int*)d_in[1];
    const int B = in_sizes[1];            // 4096
    const int D = in_sizes[0] / B;        // 1024
    const int nb = B / 128;               // 32
    const int NT = nb * (nb + 1) / 2;     // 528
    const int total4 = B * D / 4;

    char* ws = (char*)d_ws;
    unsigned char* f8 = (unsigned char*)ws;
    size_t off = (size_t)B * D;           // 4 MB fp8
    float* pmin = (float*)(ws + off); off += (size_t)64 * B * 4;   // 1 MB
    float* pmax = (float*)(ws + off); off += (size_t)64 * B * 4;   // 1 MB
    float* psP  = (float*)(ws + off); off += (size_t)64 * B * 4;   // 1 MB
    float* psN  = (float*)(ws + off); off += (size_t)64 * B * 4;   // 1 MB
    unsigned* cnt = (unsigned*)(ws + ((off + 255) & ~(size_t)255));
    float* outp = (float*)d_out;

    k_init<<<(total4 + 255) / 256, 256, 0, stream>>>(feats, f8, outp, cnt, total4);

    // 528 blocks x 256 thr — fused GEMM + stats + grid-sync + exp sums (R22)
    k_fused<<<NT, 256, 0, stream>>>(f8, labels, pmin, pmax, psP, psN, cnt, D, nb, NT);

    // final: 16 blocks, one atomic each
    k_final<<<B / 256, 256, 0, stream>>>(psP, psN, outp, B);
}

// Round 7
// 134.673 us; speedup vs baseline: 1.1885x; 1.1885x over previous
//
#include <hip/hip_runtime.h>

typedef _Float16 half8 __attribute__((ext_vector_type(8)));
typedef float floatx4 __attribute__((ext_vector_type(4)));
typedef int intx4 __attribute__((ext_vector_type(4)));
typedef int intx8 __attribute__((ext_vector_type(8)));
typedef __attribute__((address_space(1))) const void gvoid;
typedef __attribute__((address_space(3))) void svoid;

#define SCALE_POS 2.0f
#define SCALE_NEG 40.0f
#define THRESH 0.5f
#define MARGIN 0.1f
#define EPSV 1e-5f

// ---- kernel 1: fp32 -> fp8 e4m3 (OCP, RNE via HW cvt) + out zero ----
__global__ void k_init(const float* __restrict__ feats,
                       unsigned char* __restrict__ f8,
                       float* __restrict__ out,
                       int total4) {
    int i = blockIdx.x * blockDim.x + threadIdx.x;
    if (i < total4) {
        float4 v = ((const float4*)feats)[i];
        int w = 0;
        w = __builtin_amdgcn_cvt_pk_fp8_f32(v.x, v.y, w, false);  // bytes 0,1
        w = __builtin_amdgcn_cvt_pk_fp8_f32(v.z, v.w, w, true);   // bytes 2,3
        ((int*)f8)[i] = w;
    }
    if (i == 0) out[0] = 0.f;
}

// =====================================================================
// kernel 2 (R23 = R20 verbatim, the measured-best 134.7us config):
// MX-fp8 symmetric GEMM over FULL 128x128 tiles, 528 blocks x 256 thr
// (4 waves 2x2), gload_lds staging, XCD swizzle, unique-writer stat
// partials. Six K-loop/staging variants (R14/R17/R18/R19/R20/R21)
// measured equal within noise — this is the VGPR-cheapest (64).
// R22's fused variant proved the phase cost is structure-insensitive,
// so this kernel is left untouched.
// =====================================================================
__global__ void __launch_bounds__(256, 4)
k_gemm_h(const unsigned char* __restrict__ f8,
         const int* __restrict__ labels,
         float* __restrict__ pmin,     // [64][B] partial min-pos
         float* __restrict__ pmax,     // [64][B] partial max-neg
         _Float16* __restrict__ simh,
         int D, int nb) {      // D = 1024 elements = 1024 bytes/row
    __shared__ __align__(16) unsigned char As[128 * 128];  // 16 KB
    __shared__ __align__(16) unsigned char Bs[128 * 128];  // 16 KB
    __shared__ int labR[128], labC[128];

    const int Bsz = nb * 128;

    // bijective XCD-aware swizzle: 528 tiles = 8 XCDs x 66
    const int bid0 = blockIdx.x;
    const int t = (bid0 & 7) * 66 + (bid0 >> 3);
    int rb = 0, rem = t;
    while (rem >= nb - rb) { rem -= nb - rb; ++rb; }
    const int cb = rb + rem;
    const int rowBase = rb * 128;
    const int colBase = cb * 128;

    const int tid = threadIdx.x;        // 0..255
    const int lane = tid & 63;
    const int wave = tid >> 6;          // 0..3
    const int wr = wave >> 1;           // row half of output tile
    const int wc = wave & 1;            // col half of output tile
    const int q = lane >> 4;
    const int cIn = lane & 15;

    if (tid < 128) labR[tid] = labels[rowBase + tid];
    else           labC[tid - 128] = labels[colBase + (tid - 128)];

    // staging: 32 chunks of 1KB (8 rows x 128B). Wave handles 8.
    const int subrow = lane >> 3;
    const int swz = (lane & 7) ^ subrow;     // logical 16B-block index
    const unsigned char* gP[8];
    unsigned char* lP[8];
#pragma unroll
    for (int j = 0; j < 8; ++j) {
        const int c = wave * 8 + j;          // 0..31
        const int grow = (c < 16) ? (rowBase + c * 8 + subrow)
                                  : (colBase + (c - 16) * 8 + subrow);
        gP[j] = f8 + (size_t)grow * D + swz * 16;
        lP[j] = ((c < 16) ? (As + c * 1024) : (Bs + (c - 16) * 1024)) + lane * 16;
    }

    // fragment LDS offsets: row r, 32B k-group q = logical blocks 2q,2q+1
    // physical p = blk ^ (r&7)
    int aOff0[4], aOff1[4], bOff0[4], bOff1[4];
#pragma unroll
    for (int i = 0; i < 4; ++i) {
        const int rA = wr * 64 + i * 16 + cIn;
        aOff0[i] = rA * 128 + ((2 * q) ^ (rA & 7)) * 16;
        aOff1[i] = rA * 128 + ((2 * q + 1) ^ (rA & 7)) * 16;
        const int rB = wc * 64 + i * 16 + cIn;
        bOff0[i] = rB * 128 + ((2 * q) ^ (rB & 7)) * 16;
        bOff1[i] = rB * 128 + ((2 * q + 1) ^ (rB & 7)) * 16;
    }

    floatx4 acc[4][4] = {};

    const int KT = D >> 7;               // 8 iters of K=128
    for (int kt = 0; kt < KT; ++kt) {
        const int kOff = kt * 128;
        __syncthreads();                 // prev readers done (+labels at kt=0)
#pragma unroll
        for (int j = 0; j < 8; ++j)
            __builtin_amdgcn_global_load_lds((gvoid*)(gP[j] + kOff), (svoid*)lP[j], 16, 0, 0);
        __syncthreads();                 // stage landed (implicit vmcnt drain)

        intx8 a[4], b[4];
#pragma unroll
        for (int i = 0; i < 4; ++i) {
            intx4 lo = *(const intx4*)(As + aOff0[i]);
            intx4 hi = *(const intx4*)(As + aOff1[i]);
            a[i] = __builtin_shufflevector(lo, hi, 0, 1, 2, 3, 4, 5, 6, 7);
        }
#pragma unroll
        for (int i = 0; i < 4; ++i) {
            intx4 lo = *(const intx4*)(Bs + bOff0[i]);
            intx4 hi = *(const intx4*)(Bs + bOff1[i]);
            b[i] = __builtin_shufflevector(lo, hi, 0, 1, 2, 3, 4, 5, 6, 7);
        }
#pragma unroll
        for (int i = 0; i < 4; ++i)
#pragma unroll
            for (int j2 = 0; j2 < 4; ++j2)
                acc[i][j2] = __builtin_amdgcn_mfma_scale_f32_16x16x128_f8f6f4(
                    a[i], b[j2], acc[i][j2], 0, 0,       // cbsz=fp8, blgp=fp8
                    0, 0x7f7f7f7f,                       // opsel_a, scale_a (unity E8M0)
                    0, 0x7f7f7f7f);                      // opsel_b, scale_b
    }

    int rLabv[16];
#pragma unroll
    for (int mi = 0; mi < 4; ++mi)
#pragma unroll
        for (int rr = 0; rr < 4; ++rr)
            rLabv[mi * 4 + rr] = labR[wr * 64 + mi * 16 + q * 4 + rr];
    int cLabv[4];
#pragma unroll
    for (int ni = 0; ni < 4; ++ni)
        cLabv[ni] = labC[wc * 64 + ni * 16 + cIn];

    // ---- fp16 store: identical per-64-col-half layout to R13/R14 ----
    {
        half8* dst = (half8*)(simh + (size_t)(2 * t + wc) * 8192
                                   + (size_t)(wr * 64 + lane) * 64);
#pragma unroll
        for (int mi = 0; mi < 4; ++mi) {
            half8 h0, h1;
#pragma unroll
            for (int ni = 0; ni < 2; ++ni)
#pragma unroll
                for (int rr = 0; rr < 4; ++rr) {
                    h0[ni * 4 + rr] = (_Float16)acc[mi][ni][rr];
                    h1[ni * 4 + rr] = (_Float16)acc[mi][ni + 2][rr];
                }
            dst[mi * 2] = h0;
            dst[mi * 2 + 1] = h1;
        }
    }

    // ---- row stats partials: slot (2*cb+wc), plain stores ----
    {
        float* pmnRow = pmin + (size_t)(2 * cb + wc) * Bsz + rowBase;
        float* pmxRow = pmax + (size_t)(2 * cb + wc) * Bsz + rowBase;
#pragma unroll
        for (int mi = 0; mi < 4; ++mi)
#pragma unroll
            for (int rr = 0; rr < 4; ++rr) {
                const int rLoc = wr * 64 + mi * 16 + q * 4 + rr;
                const int rLab = rLabv[mi * 4 + rr];
                float vmin = 1e30f, vmax = -1e30f;
#pragma unroll
                for (int ni = 0; ni < 4; ++ni) {
                    float s = acc[mi][ni][rr];
                    if (rLab == cLabv[ni]) {
                        if (s < 1.0f - EPSV) vmin = fminf(vmin, s);
                    } else {
                        vmax = fmaxf(vmax, s);
                    }
                }
#pragma unroll
                for (int off = 8; off; off >>= 1) {
                    vmin = fminf(vmin, __shfl_xor(vmin, off, 16));
                    vmax = fmaxf(vmax, __shfl_xor(vmax, off, 16));
                }
                if (cIn == 0) {
                    pmnRow[rLoc] = vmin;
                    pmxRow[rLoc] = vmax;
                }
            }
    }

    // ---- col stats partials via symmetry (off-diag only): slot (2*rb+wr) ----
    if (rb != cb) {
        float* pmnCol = pmin + (size_t)(2 * rb + wr) * Bsz + colBase;
        float* pmxCol = pmax + (size_t)(2 * rb + wr) * Bsz + colBase;
#pragma unroll
        for (int ni = 0; ni < 4; ++ni) {
            const int cLab = cLabv[ni];
            float vmin = 1e30f, vmax = -1e30f;
#pragma unroll
            for (int mi = 0; mi < 4; ++mi)
#pragma unroll
                for (int rr = 0; rr < 4; ++rr) {
                    float s = acc[mi][ni][rr];
                    if (rLabv[mi * 4 + rr] == cLab) {
                        if (s < 1.0f - EPSV) vmin = fminf(vmin, s);
                    } else {
                        vmax = fmaxf(vmax, s);
                    }
                }
            vmin = fminf(vmin, __shfl_xor(vmin, 16, 64));
            vmin = fminf(vmin, __shfl_xor(vmin, 32, 64));
            vmax = fmaxf(vmax, __shfl_xor(vmax, 16, 64));
            vmax = fmaxf(vmax, __shfl_xor(vmax, 32, 64));
            if (q == 0) {
                const int cLoc = wc * 64 + ni * 16 + cIn;
                pmnCol[cLoc] = vmin;
                pmxCol[cLoc] = vmax;
            }
        }
    }
}

// =====================================================================
// kernel 3 (R23): pass 2 with FUSED gate prologue (was kernel k_stats).
// Each block computes the gates for exactly its 128 rows + 128 cols
// directly from pmin/pmax (written by k_gemm_h, stream-ordered, so
// visible). tid<128: row gates; tid>=128: col gates. Coalesced:
// consecutive tid -> consecutive addresses per k-slot. Then the R20
// verified gated-exp-sum body, unique-writer psP/psN slots. 5->4
// dispatches total.
// =====================================================================
__global__ void __launch_bounds__(256)
k_sum2f(const _Float16* __restrict__ simh,
        const int* __restrict__ labels,
        const float* __restrict__ pmin,
        const float* __restrict__ pmax,
        float* __restrict__ psP, float* __restrict__ psN,
        int nb, int B) {
    __shared__ int labR[128], labC[128];
    __shared__ float gNR[128], gPR[128], gNC[128], gPC[128];

    int t = blockIdx.x;
    int rb = 0, rem = t;
    while (rem >= nb - rb) { rem -= nb - rb; ++rb; }
    const int cb = rb + rem;
    const int rowBase = rb * 128;

    const int tid = threadIdx.x;
    const int sub = tid >> 7;           // 0..1 : col half
    const int stid = tid & 127;
    const int wave = stid >> 6;         // 0..1 : row half within sub
    const int lane = tid & 63;
    const int q = lane >> 4;
    const int cIn = lane & 15;
    const int colBase = cb * 128 + sub * 64;

    // ---- fused gate prologue (replaces the k_stats dispatch) ----
    {
        const int j = tid & 127;
        const int base = (tid < 128) ? (rowBase + j) : (cb * 128 + j);
        float mn = 1e30f, mx = -1e30f;
#pragma unroll 4
        for (int k = 0; k < 64; ++k) {
            mn = fminf(mn, pmin[(size_t)k * B + base]);
            mx = fmaxf(mx, pmax[(size_t)k * B + base]);
        }
        if (tid < 128) {
            labR[j] = labels[rowBase + j];
            gNR[j] = mn - MARGIN;       // neg kept if s > gNR
            gPR[j] = mx + MARGIN;       // pos kept if s < gPR
        } else {
            labC[j] = labels[cb * 128 + j];
            gNC[j] = mn - MARGIN;
            gPC[j] = mx + MARGIN;
        }
    }
    __syncthreads();

    int cLabv[4];
    float gNCv[4], gPCv[4];
#pragma unroll
    for (int ni = 0; ni < 4; ++ni) {
        const int j = sub * 64 + ni * 16 + cIn;
        cLabv[ni] = labC[j];
        gNCv[ni] = gNC[j];
        gPCv[ni] = gPC[j];
    }

    const half8* src = (const half8*)(simh + (size_t)(2 * t + sub) * 8192 + (size_t)stid * 64);
    half8 hv[8];
#pragma unroll
    for (int v = 0; v < 8; ++v) hv[v] = src[v];

    float cps[4] = {}, cns[4] = {};
    const bool offd = (rb != cb);

    float* psPRow = psP + (size_t)(2 * cb + sub) * B + rowBase;
    float* psNRow = psN + (size_t)(2 * cb + sub) * B + rowBase;

#pragma unroll
    for (int mi = 0; mi < 4; ++mi)
#pragma unroll
        for (int rr = 0; rr < 4; ++rr) {
            const int rLoc = wave * 64 + mi * 16 + q * 4 + rr;
            const int rLab = labR[rLoc];
            const float gn = gNR[rLoc];
            const float gp = gPR[rLoc];
            float rp = 0.f, rn = 0.f;
#pragma unroll
            for (int ni = 0; ni < 4; ++ni) {
                const int idx = mi * 16 + ni * 4 + rr;
                const float s = (float)hv[idx >> 3][idx & 7];
                if (rLab == cLabv[ni]) {
                    if (s < 1.0f - EPSV) {
                        float ev = __expf(-SCALE_POS * (s - THRESH));
                        if (s < gp) rp += ev;
                        if (offd && s < gPCv[ni]) cps[ni] += ev;
                    }
                } else {
                    float ev = __expf(SCALE_NEG * (s - THRESH));
                    if (s > gn) rn += ev;
                    if (offd && s > gNCv[ni]) cns[ni] += ev;
                }
            }
#pragma unroll
            for (int off = 8; off; off >>= 1) {
                rp += __shfl_xor(rp, off, 16);
                rn += __shfl_xor(rn, off, 16);
            }
            if (cIn == 0) {
                psPRow[rLoc] = rp;      // unique slot, plain store
                psNRow[rLoc] = rn;
            }
        }
    if (offd) {
        float* psPCol = psP + (size_t)(2 * rb + wave) * B + colBase;
        float* psNCol = psN + (size_t)(2 * rb + wave) * B + colBase;
#pragma unroll
        for (int ni = 0; ni < 4; ++ni) {
            cps[ni] += __shfl_xor(cps[ni], 16, 64);
            cps[ni] += __shfl_xor(cps[ni], 32, 64);
            cns[ni] += __shfl_xor(cns[ni], 16, 64);
            cns[ni] += __shfl_xor(cns[ni], 32, 64);
            if (q == 0) {
                const int cLoc = ni * 16 + cIn;
                psPCol[cLoc] = cps[ni];
                psNCol[cLoc] = cns[ni];
            }
        }
    }
}

// =====================================================================
// kernel 4: final reduce -> out[0] (16 blocks, one atomicAdd each)
// =====================================================================
__global__ void __launch_bounds__(256)
k_final(const float* __restrict__ psP, const float* __restrict__ psN,
        float* __restrict__ out, int B) {
    __shared__ float red[4];
    const int r = blockIdx.x * 256 + threadIdx.x;
    float P = 0.f, N = 0.f;
    for (int k = 0; k < 64; ++k) {
        P += psP[(size_t)k * B + r];
        N += psN[(size_t)k * B + r];
    }
    float a = (P > 0.f && N > 0.f)
                  ? log1pf(P) * (1.0f / SCALE_POS) + log1pf(N) * (1.0f / SCALE_NEG)
                  : 0.f;
#pragma unroll
    for (int off = 32; off; off >>= 1) a += __shfl_down(a, off, 64);
    const int tid = threadIdx.x;
    if ((tid & 63) == 0) red[tid >> 6] = a;
    __syncthreads();
    if (tid == 0)
        atomicAdd(out, (red[0] + red[1] + red[2] + red[3]) / (float)B);
}

extern "C" void kernel_launch(void* const* d_in, const int* in_sizes, int n_in,
                              void* d_out, int out_size, void* d_ws, size_t ws_size,
                              hipStream_t stream) {
    const float* feats = (const float*)d_in[0];
    const int* labels = (const int*)d_in[1];
    const int B = in_sizes[1];            // 4096
    const int D = in_sizes[0] / B;        // 1024
    const int nb = B / 128;               // 32
    const int NT = nb * (nb + 1) / 2;     // 528
    const int total4 = B * D / 4;

    char* ws = (char*)d_ws;
    unsigned char* f8 = (unsigned char*)ws;
    size_t off = (size_t)B * D;           // 4 MB fp8
    float* pmin = (float*)(ws + off); off += (size_t)64 * B * 4;   // 1 MB
    float* pmax = (float*)(ws + off); off += (size_t)64 * B * 4;   // 1 MB
    float* psP  = (float*)(ws + off); off += (size_t)64 * B * 4;   // 1 MB
    float* psN  = (float*)(ws + off); off += (size_t)64 * B * 4;   // 1 MB
    _Float16* simh = (_Float16*)(ws + ((off + 255) & ~(size_t)255));
    float* outp = (float*)d_out;

    k_init<<<(total4 + 255) / 256, 256, 0, stream>>>(feats, f8, outp, total4);

    // 528 blocks x 256 thr — full-tile MX-fp8 GEMM + stat partials (R20 verbatim)
    k_gemm_h<<<NT, 256, 0, stream>>>(f8, labels, pmin, pmax, simh, D, nb);

    // pass 2: 528 blocks x 256 thr, fused gate prologue + partial-slot sums
    k_sum2f<<<NT, 256, 0, stream>>>(simh, labels, pmin, pmax, psP, psN, nb, B);

    // final: 16 blocks, one atomic each
    k_final<<<B / 256, 256, 0, stream>>>(psP, psN, outp, B);
}